// Round 1
// baseline (1745.354 us; speedup 1.0000x reference)
//
#include <hip/hip_runtime.h>
#include <math.h>

#define N_NODES 32768
#define F_IN    128
#define C_CH    4
#define H_HEADS 8
#define D_DIM   32
#define DM      256
#define E_BOND  65536
#define B_BRIDGE 8192
#define ET      (E_BOND + 2*B_BRIDGE)   // 81920
#define OUTC    1024                    // C*H*D

// ---- workspace layout (bytes) ----
#define WS_XL     0u
#define WS_PE     33554432u             // N*DM*4
#define WS_SCORES 33558528u             // +1024*4
#define WS_DENOM  44044288u             // +ET*32*4
#define WS_GMAX   48238592u             // +N*32*4

__device__ __forceinline__ unsigned enc_f32(float f) {
    unsigned u = __float_as_uint(f);
    return (u & 0x80000000u) ? ~u : (u | 0x80000000u);
}
__device__ __forceinline__ float dec_f32(unsigned u) {
    return (u & 0x80000000u) ? __uint_as_float(u & 0x7fffffffu) : __uint_as_float(~u);
}
__device__ __forceinline__ float dot4(float4 a, float4 b) {
    return a.x*b.x + a.y*b.y + a.z*b.z + a.w*b.w;
}
__device__ __forceinline__ float leaky(float v) { return v >= 0.f ? v : 0.2f*v; }

// ---------------- pe + gmax init ----------------
__global__ void pe_init_kernel(float* __restrict__ pe, unsigned* __restrict__ gmax) {
    int tid = threadIdx.x;              // 1024
    int c = tid >> 8, p = tid & 255;
    float expo = (float)(p & ~1) * (1.0f/256.0f);
    float div  = powf(10000.0f, expo);
    float arg  = (float)c / div;
    pe[tid] = (p & 1) ? cosf(arg) : sinf(arg);
    if (tid == 0) *gmax = 0u;           // encodes "below all finite floats"
}

// ---------------- GEMM: out[n, col] = sum_k x[n,k]*W[col,k] ----------------
// block: 256 threads, 32 nodes/block; PASSES*256 cols.
template<int PASSES>
__global__ __launch_bounds__(256) void gemm_nodes(const float* __restrict__ x,
        const float* __restrict__ W, float* __restrict__ out, int ldo) {
    __shared__ float xs[32][128];
    const int tid = threadIdx.x;
    const long node0 = (long)blockIdx.x * 32;
    const float4* xg = (const float4*)(x + node0 * F_IN);
    float4* xs4 = (float4*)&xs[0][0];
#pragma unroll
    for (int i = 0; i < 4; ++i) xs4[tid + 256*i] = xg[tid + 256*i];
    __syncthreads();
    const int tx = tid & 63, ty = tid >> 6;
    for (int pass = 0; pass < PASSES; ++pass) {
        const int col0 = pass*256 + tx*4;
        const float* Wr = W + (long)col0 * F_IN;
        float acc[8][4];
#pragma unroll
        for (int nn = 0; nn < 8; ++nn)
            acc[nn][0] = acc[nn][1] = acc[nn][2] = acc[nn][3] = 0.f;
#pragma unroll 4
        for (int k4 = 0; k4 < 32; ++k4) {
            float4 w0 = *(const float4*)(Wr + 0*F_IN + k4*4);
            float4 w1 = *(const float4*)(Wr + 1*F_IN + k4*4);
            float4 w2 = *(const float4*)(Wr + 2*F_IN + k4*4);
            float4 w3 = *(const float4*)(Wr + 3*F_IN + k4*4);
#pragma unroll
            for (int nn = 0; nn < 8; ++nn) {
                float4 xv = *(const float4*)&xs[ty*8+nn][k4*4];
                acc[nn][0] += dot4(w0, xv);
                acc[nn][1] += dot4(w1, xv);
                acc[nn][2] += dot4(w2, xv);
                acc[nn][3] += dot4(w3, xv);
            }
        }
#pragma unroll
        for (int nn = 0; nn < 8; ++nn) {
            long n = node0 + ty*8 + nn;
            *(float4*)(out + n*ldo + col0) =
                make_float4(acc[nn][0], acc[nn][1], acc[nn][2], acc[nn][3]);
        }
    }
}

// ---------------- scores + global max ----------------
// thread = (edge, ch) pair; ch = c*H + h
__global__ __launch_bounds__(256) void scores_kernel(
        const float* __restrict__ xl, const float* __restrict__ pe,
        const int* __restrict__ ei, const int* __restrict__ bi,
        const float* __restrict__ datt, float* __restrict__ scores,
        unsigned* __restrict__ gmax) {
    const int idx = blockIdx.x * 256 + threadIdx.x;
    const int e = idx >> 5, ch = idx & 31;
    const int c = ch >> 3, h = ch & 7;
    int nA, cA, nB, cB; bool zero = false;
    if (e < E_BOND) {
        nA = ei[e]; cA = c; nB = ei[E_BOND + e]; cB = c;
    } else if (e < E_BOND + B_BRIDGE) {
        int i = e - E_BOND;
        nA = bi[B_BRIDGE + i]; cA = c;                 // dst_bridge, chain c
        nB = bi[i];            cB = (c+1 < C_CH-1) ? c+1 : C_CH-1; // src_bridge, next_ch
        zero = (c == C_CH-1);
    } else {
        int i = e - E_BOND - B_BRIDGE;
        nA = bi[i];            cA = c;                 // src_bridge, chain c
        nB = bi[B_BRIDGE + i]; cB = (c-1 > 0) ? c-1 : 0; // dst_bridge, prev_ch
        zero = (c == 0);
    }
    float score = 0.f;
    if (!zero) {
        const float4* a4 = (const float4*)(xl + (long)nA*DM + h*D_DIM);
        const float4* b4 = (const float4*)(xl + (long)nB*DM + h*D_DIM);
        const float4* pa = (const float4*)(pe + cA*DM + h*D_DIM);
        const float4* pb = (const float4*)(pe + cB*DM + h*D_DIM);
        const float4* w4 = (const float4*)(datt + ch*D_DIM);
#pragma unroll
        for (int q = 0; q < 8; ++q) {
            float4 va = a4[q], vb = b4[q], fa = pa[q], fb = pb[q], w = w4[q];
            score += w.x * leaky(va.x + fa.x + vb.x + fb.x);
            score += w.y * leaky(va.y + fa.y + vb.y + fb.y);
            score += w.z * leaky(va.z + fa.z + vb.z + fb.z);
            score += w.w * leaky(va.w + fa.w + vb.w + fb.w);
        }
    }
    scores[idx] = score;
    // block max -> encoded atomicMax
    float m = score;
#pragma unroll
    for (int off = 32; off > 0; off >>= 1)
        m = fmaxf(m, __shfl_down(m, off, 64));
    __shared__ float sm[4];
    const int lane = threadIdx.x & 63, wv = threadIdx.x >> 6;
    if (lane == 0) sm[wv] = m;
    __syncthreads();
    if (threadIdx.x == 0) {
        float mm = fmaxf(fmaxf(sm[0], sm[1]), fmaxf(sm[2], sm[3]));
        atomicMax(gmax, enc_f32(mm));
    }
}

// ---------------- exp(s - max) in place + denom scatter ----------------
__global__ __launch_bounds__(256) void expdenom_kernel(
        float* __restrict__ scores, const int* __restrict__ ei,
        const int* __restrict__ bi, float* __restrict__ denom,
        const unsigned* __restrict__ gmax) {
    const int idx = blockIdx.x * 256 + threadIdx.x;
    const float m = dec_f32(*gmax);
    const int e = idx >> 5, ch = idx & 31;
    int dst;
    if (e < E_BOND)               dst = ei[E_BOND + e];
    else if (e < E_BOND+B_BRIDGE) dst = bi[B_BRIDGE + (e - E_BOND)];
    else                          dst = bi[e - E_BOND - B_BRIDGE];
    float v = expf(scores[idx] - m);
    scores[idx] = v;
    atomicAdd(denom + (long)dst*32 + ch, v);
}

// ---------------- aggregation: scatter alpha * xr[g] into out ----------------
// block = 1 edge, 256 threads x 4 consecutive floats = 1024 values
__global__ __launch_bounds__(256) void agg_kernel(
        const float* __restrict__ xl, const float* __restrict__ pe,
        const int* __restrict__ ei, const int* __restrict__ bi,
        const float* __restrict__ expq, const float* __restrict__ denom,
        float* __restrict__ out) {
    const int e = blockIdx.x;
    int dst, fs;
    if (e < E_BOND)               { dst = ei[E_BOND+e];  fs = ei[e]; }
    else if (e < E_BOND+B_BRIDGE) { int i = e-E_BOND;    dst = bi[B_BRIDGE+i]; fs = bi[i]; }
    else                          { int i = e-E_BOND-B_BRIDGE; dst = bi[i]; fs = bi[B_BRIDGE+i]; }
    const int g = ei[fs];   // bug-faithful: x_src[full_src] == xr[src_bond[full_src]]
    const int t = threadIdx.x;
    const int ch = t >> 3;
    const int d0 = (t & 7) * 4;
    const int h = ch & 7, c = ch >> 3;
    const float a = expq[(long)e*32 + ch] / (denom[(long)dst*32 + ch] + 1e-16f);
    float4 xv = *(const float4*)(xl + (long)g*DM + h*D_DIM + d0);
    float4 pv = *(const float4*)(pe + c*DM + h*D_DIM + d0);
    float* o = out + (long)dst*OUTC + ch*D_DIM + d0;
    atomicAdd(o + 0, a*(xv.x + pv.x));
    atomicAdd(o + 1, a*(xv.y + pv.y));
    atomicAdd(o + 2, a*(xv.z + pv.z));
    atomicAdd(o + 3, a*(xv.w + pv.w));
}

// ---------------- epilogue: +bias, PReLU ----------------
__global__ __launch_bounds__(256) void epilogue_kernel(
        float* __restrict__ out, const float* __restrict__ bias,
        const float* __restrict__ pw) {
    const long idx = (long)blockIdx.x*256 + threadIdx.x;   // float4 index
    const float w = *pw;
    float4 v = ((float4*)out)[idx];
    const int col = ((int)(idx*4)) & (OUTC-1);
    const float4 b = *(const float4*)(bias + col);
    float r0 = v.x + b.x, r1 = v.y + b.y, r2 = v.z + b.z, r3 = v.w + b.w;
    r0 = r0 >= 0.f ? r0 : w*r0;
    r1 = r1 >= 0.f ? r1 : w*r1;
    r2 = r2 >= 0.f ? r2 : w*r2;
    r3 = r3 >= 0.f ? r3 : w*r3;
    ((float4*)out)[idx] = make_float4(r0, r1, r2, r3);
}

extern "C" void kernel_launch(void* const* d_in, const int* in_sizes, int n_in,
                              void* d_out, int out_size, void* d_ws, size_t ws_size,
                              hipStream_t stream) {
    const float* x     = (const float*)d_in[0];
    const int*   ei    = (const int*)d_in[1];
    const int*   bi    = (const int*)d_in[2];
    const float* W_in  = (const float*)d_in[3];
    const float* datt  = (const float*)d_in[4];
    const float* W_res = (const float*)d_in[5];
    const float* bias  = (const float*)d_in[6];
    const float* pw    = (const float*)d_in[7];
    float* out = (float*)d_out;
    char*  ws  = (char*)d_ws;

    float*    xl     = (float*)(ws + WS_XL);
    float*    pe     = (float*)(ws + WS_PE);
    float*    scores = (float*)(ws + WS_SCORES);
    float*    denom  = (float*)(ws + WS_DENOM);
    unsigned* gmax   = (unsigned*)(ws + WS_GMAX);

    hipMemsetAsync(denom, 0, (size_t)N_NODES*32*4, stream);
    pe_init_kernel<<<1, 1024, 0, stream>>>(pe, gmax);
    gemm_nodes<1><<<N_NODES/32, 256, 0, stream>>>(x, W_in, xl, DM);
    gemm_nodes<4><<<N_NODES/32, 256, 0, stream>>>(x, W_res, out, OUTC);
    scores_kernel<<<ET*32/256, 256, 0, stream>>>(xl, pe, ei, bi, datt, scores, gmax);
    expdenom_kernel<<<ET*32/256, 256, 0, stream>>>(scores, ei, bi, denom, gmax);
    agg_kernel<<<ET, 256, 0, stream>>>(xl, pe, ei, bi, scores, denom, out);
    epilogue_kernel<<<(N_NODES*OUTC)/4/256, 256, 0, stream>>>(out, bias, pw);
}

// Round 2
// 689.289 us; speedup vs baseline: 2.5321x; 2.5321x over previous
//
#include <hip/hip_runtime.h>
#include <math.h>

#define N_NODES 32768
#define F_IN    128
#define C_CH    4
#define H_HEADS 8
#define D_DIM   32
#define DM      256
#define E_BOND  65536
#define B_BRIDGE 8192
#define ET      (E_BOND + 2*B_BRIDGE)   // 81920
#define OUTC    1024                    // C*H*D
#define CAP     24                      // bucket capacity per dst node (max degree ~15)

// ---- workspace layout (bytes) ----
#define WS_XL     0u
#define WS_PE     33554432u             // + N*DM*4
#define WS_SCORES 33558528u             // + 1024*4
#define WS_GSRC   44044288u             // + ET*32*4
#define WS_CNT    44371968u             // + ET*4
#define WS_BUCKET 44503040u             // + N*4
#define WS_GMAX   47648768u             // + N*CAP*4

__device__ __forceinline__ unsigned enc_f32(float f) {
    unsigned u = __float_as_uint(f);
    return (u & 0x80000000u) ? ~u : (u | 0x80000000u);
}
__device__ __forceinline__ float dec_f32(unsigned u) {
    return (u & 0x80000000u) ? __uint_as_float(u & 0x7fffffffu) : __uint_as_float(~u);
}
__device__ __forceinline__ float dot4(float4 a, float4 b) {
    return a.x*b.x + a.y*b.y + a.z*b.z + a.w*b.w;
}
__device__ __forceinline__ float leaky(float v) { return v >= 0.f ? v : 0.2f*v; }

// decode edge e -> (dst node, full_src value fs)
__device__ __forceinline__ void edge_decode(int e, const int* __restrict__ ei,
                                            const int* __restrict__ bi,
                                            int& dst, int& fs) {
    if (e < E_BOND)               { dst = ei[E_BOND+e];  fs = ei[e]; }
    else if (e < E_BOND+B_BRIDGE) { int i = e-E_BOND;    dst = bi[B_BRIDGE+i]; fs = bi[i]; }
    else                          { int i = e-E_BOND-B_BRIDGE; dst = bi[i]; fs = bi[B_BRIDGE+i]; }
}

// ---------------- pe + gmax init ----------------
__global__ void pe_init_kernel(float* __restrict__ pe, unsigned* __restrict__ gmax) {
    int tid = threadIdx.x;              // 1024
    int c = tid >> 8, p = tid & 255;
    float expo = (float)(p & ~1) * (1.0f/256.0f);
    float div  = powf(10000.0f, expo);
    float arg  = (float)c / div;
    pe[tid] = (p & 1) ? cosf(arg) : sinf(arg);
    if (tid == 0) *gmax = 0u;           // encodes "below all finite floats"
}

// ---------------- GEMM: out[n, col] = sum_k x[n,k]*W[col,k] ----------------
template<int PASSES>
__global__ __launch_bounds__(256) void gemm_nodes(const float* __restrict__ x,
        const float* __restrict__ W, float* __restrict__ out, int ldo) {
    __shared__ float xs[32][128];
    const int tid = threadIdx.x;
    const long node0 = (long)blockIdx.x * 32;
    const float4* xg = (const float4*)(x + node0 * F_IN);
    float4* xs4 = (float4*)&xs[0][0];
#pragma unroll
    for (int i = 0; i < 4; ++i) xs4[tid + 256*i] = xg[tid + 256*i];
    __syncthreads();
    const int tx = tid & 63, ty = tid >> 6;
    for (int pass = 0; pass < PASSES; ++pass) {
        const int col0 = pass*256 + tx*4;
        const float* Wr = W + (long)col0 * F_IN;
        float acc[8][4];
#pragma unroll
        for (int nn = 0; nn < 8; ++nn)
            acc[nn][0] = acc[nn][1] = acc[nn][2] = acc[nn][3] = 0.f;
#pragma unroll 4
        for (int k4 = 0; k4 < 32; ++k4) {
            float4 w0 = *(const float4*)(Wr + 0*F_IN + k4*4);
            float4 w1 = *(const float4*)(Wr + 1*F_IN + k4*4);
            float4 w2 = *(const float4*)(Wr + 2*F_IN + k4*4);
            float4 w3 = *(const float4*)(Wr + 3*F_IN + k4*4);
#pragma unroll
            for (int nn = 0; nn < 8; ++nn) {
                float4 xv = *(const float4*)&xs[ty*8+nn][k4*4];
                acc[nn][0] += dot4(w0, xv);
                acc[nn][1] += dot4(w1, xv);
                acc[nn][2] += dot4(w2, xv);
                acc[nn][3] += dot4(w3, xv);
            }
        }
#pragma unroll
        for (int nn = 0; nn < 8; ++nn) {
            long n = node0 + ty*8 + nn;
            *(float4*)(out + n*ldo + col0) =
                make_float4(acc[nn][0], acc[nn][1], acc[nn][2], acc[nn][3]);
        }
    }
}

// ---------------- scores + global max ----------------
__global__ __launch_bounds__(256) void scores_kernel(
        const float* __restrict__ xl, const float* __restrict__ pe,
        const int* __restrict__ ei, const int* __restrict__ bi,
        const float* __restrict__ datt, float* __restrict__ scores,
        unsigned* __restrict__ gmax) {
    const int idx = blockIdx.x * 256 + threadIdx.x;
    const int e = idx >> 5, ch = idx & 31;
    const int c = ch >> 3, h = ch & 7;
    int nA, cA, nB, cB; bool zero = false;
    if (e < E_BOND) {
        nA = ei[e]; cA = c; nB = ei[E_BOND + e]; cB = c;
    } else if (e < E_BOND + B_BRIDGE) {
        int i = e - E_BOND;
        nA = bi[B_BRIDGE + i]; cA = c;
        nB = bi[i];            cB = (c+1 < C_CH-1) ? c+1 : C_CH-1;
        zero = (c == C_CH-1);
    } else {
        int i = e - E_BOND - B_BRIDGE;
        nA = bi[i];            cA = c;
        nB = bi[B_BRIDGE + i]; cB = (c-1 > 0) ? c-1 : 0;
        zero = (c == 0);
    }
    float score = 0.f;
    if (!zero) {
        const float4* a4 = (const float4*)(xl + (long)nA*DM + h*D_DIM);
        const float4* b4 = (const float4*)(xl + (long)nB*DM + h*D_DIM);
        const float4* pa = (const float4*)(pe + cA*DM + h*D_DIM);
        const float4* pb = (const float4*)(pe + cB*DM + h*D_DIM);
        const float4* w4 = (const float4*)(datt + ch*D_DIM);
#pragma unroll
        for (int q = 0; q < 8; ++q) {
            float4 va = a4[q], vb = b4[q], fa = pa[q], fb = pb[q], w = w4[q];
            score += w.x * leaky(va.x + fa.x + vb.x + fb.x);
            score += w.y * leaky(va.y + fa.y + vb.y + fb.y);
            score += w.z * leaky(va.z + fa.z + vb.z + fb.z);
            score += w.w * leaky(va.w + fa.w + vb.w + fb.w);
        }
    }
    scores[idx] = score;
    float m = score;
#pragma unroll
    for (int off = 32; off > 0; off >>= 1)
        m = fmaxf(m, __shfl_down(m, off, 64));
    __shared__ float sm[4];
    const int lane = threadIdx.x & 63, wv = threadIdx.x >> 6;
    if (lane == 0) sm[wv] = m;
    __syncthreads();
    if (threadIdx.x == 0) {
        float mm = fmaxf(fmaxf(sm[0], sm[1]), fmaxf(sm[2], sm[3]));
        atomicMax(gmax, enc_f32(mm));
    }
}

// ---------------- CSR-bucket build ----------------
__global__ __launch_bounds__(256) void build_kernel(
        const int* __restrict__ ei, const int* __restrict__ bi,
        int* __restrict__ counts, int* __restrict__ bucket,
        int* __restrict__ gsrc) {
    const int e = blockIdx.x * 256 + threadIdx.x;
    if (e >= ET) return;
    int dst, fs;
    edge_decode(e, ei, bi, dst, fs);
    gsrc[e] = ei[fs];   // bug-faithful: x_src[full_src] == xr[src_bond[full_src]]
    int slot = atomicAdd(&counts[dst], 1);
    if (slot < CAP) bucket[dst*CAP + slot] = e;
}

// ---------------- gather: denom + aggregation + residual + bias + PReLU ----
// block = 1 dst node, 256 threads = (ch, d0) slices of the 1024-wide output
__global__ __launch_bounds__(256) void gather_kernel(
        const float* __restrict__ xl, const float* __restrict__ pe,
        const float* __restrict__ scores, const int* __restrict__ counts,
        const int* __restrict__ bucket, const int* __restrict__ gsrc,
        const unsigned* __restrict__ gmax, const float* __restrict__ bias,
        const float* __restrict__ pw, float* __restrict__ out) {
    const int n = blockIdx.x;
    const int t = threadIdx.x;
    const int ch = t >> 3;
    const int d0 = (t & 7) * 4;
    const int h = ch & 7, c = ch >> 3;
    const float m = dec_f32(*gmax);
    const int cnt = min(counts[n], CAP);

    // pass 1: denominator for this (n, ch)
    float den = 0.f;
    for (int i = 0; i < cnt; ++i) {
        int e = bucket[n*CAP + i];
        den += __expf(scores[e*32 + ch] - m);
    }
    const float inv = 1.f / (den + 1e-16f);

    // pass 2: accumulate alpha * (xl[g] + pe) on top of residual
    const int col = ch*D_DIM + d0;
    float4 acc = *(const float4*)(out + (long)n*OUTC + col);
    const float4 pv = *(const float4*)(pe + c*DM + h*D_DIM + d0);
    for (int i = 0; i < cnt; ++i) {
        int e = bucket[n*CAP + i];
        float a = __expf(scores[e*32 + ch] - m) * inv;
        int g = gsrc[e];
        float4 xv = *(const float4*)(xl + (long)g*DM + h*D_DIM + d0);
        acc.x += a*(xv.x + pv.x);
        acc.y += a*(xv.y + pv.y);
        acc.z += a*(xv.z + pv.z);
        acc.w += a*(xv.w + pv.w);
    }

    const float4 b = *(const float4*)(bias + col);
    const float w = *pw;
    float r0 = acc.x + b.x, r1 = acc.y + b.y, r2 = acc.z + b.z, r3 = acc.w + b.w;
    r0 = r0 >= 0.f ? r0 : w*r0;
    r1 = r1 >= 0.f ? r1 : w*r1;
    r2 = r2 >= 0.f ? r2 : w*r2;
    r3 = r3 >= 0.f ? r3 : w*r3;
    *(float4*)(out + (long)n*OUTC + col) = make_float4(r0, r1, r2, r3);
}

extern "C" void kernel_launch(void* const* d_in, const int* in_sizes, int n_in,
                              void* d_out, int out_size, void* d_ws, size_t ws_size,
                              hipStream_t stream) {
    const float* x     = (const float*)d_in[0];
    const int*   ei    = (const int*)d_in[1];
    const int*   bi    = (const int*)d_in[2];
    const float* W_in  = (const float*)d_in[3];
    const float* datt  = (const float*)d_in[4];
    const float* W_res = (const float*)d_in[5];
    const float* bias  = (const float*)d_in[6];
    const float* pw    = (const float*)d_in[7];
    float* out = (float*)d_out;
    char*  ws  = (char*)d_ws;

    float*    xl     = (float*)(ws + WS_XL);
    float*    pe     = (float*)(ws + WS_PE);
    float*    scores = (float*)(ws + WS_SCORES);
    int*      gsrc   = (int*)(ws + WS_GSRC);
    int*      counts = (int*)(ws + WS_CNT);
    int*      bucket = (int*)(ws + WS_BUCKET);
    unsigned* gmax   = (unsigned*)(ws + WS_GMAX);

    hipMemsetAsync(counts, 0, (size_t)N_NODES*4, stream);
    pe_init_kernel<<<1, 1024, 0, stream>>>(pe, gmax);
    gemm_nodes<1><<<N_NODES/32, 256, 0, stream>>>(x, W_in, xl, DM);
    gemm_nodes<4><<<N_NODES/32, 256, 0, stream>>>(x, W_res, out, OUTC);
    scores_kernel<<<ET*32/256, 256, 0, stream>>>(xl, pe, ei, bi, datt, scores, gmax);
    build_kernel<<<(ET+255)/256, 256, 0, stream>>>(ei, bi, counts, bucket, gsrc);
    gather_kernel<<<N_NODES, 256, 0, stream>>>(xl, pe, scores, counts, bucket,
                                               gsrc, gmax, bias, pw, out);
}

// Round 3
// 423.314 us; speedup vs baseline: 4.1231x; 1.6283x over previous
//
#include <hip/hip_runtime.h>
#include <math.h>

#define N_NODES 32768
#define F_IN    128
#define C_CH    4
#define H_HEADS 8
#define D_DIM   32
#define DM      256
#define E_BOND  65536
#define B_BRIDGE 8192
#define ET      (E_BOND + 2*B_BRIDGE)   // 81920
#define OUTC    1024                    // C*H*D
#define CAP     24                      // bucket capacity per dst node
#define NCOLS   1280                    // DM + OUTC combined GEMM width

// ---- workspace layout (bytes) ----
#define WS_XL     0u
#define WS_PE     33554432u             // + N*DM*4
#define WS_SCORES 33558528u             // + 1024*4       (ET*32*4 = 10.49 MB)
#define WS_GSRC   44044288u             // + ET*32*4
#define WS_CNT    44371968u             // + ET*4
#define WS_BUCKET 44503040u             // + N*4
#define WS_GMAX   47648768u             // + N*CAP*4
// bf16 staging overlays the scores region (scores written later in-stream):
#define WS_XB     WS_SCORES             // N*128*2 = 8,388,608
#define WS_WC     (WS_SCORES + 8388608u) // NCOLS*128*2 = 327,680  (ends < WS_GSRC)

typedef __attribute__((ext_vector_type(8))) short bf16x8;
typedef __attribute__((ext_vector_type(4))) float f32x4;

__device__ __forceinline__ unsigned enc_f32(float f) {
    unsigned u = __float_as_uint(f);
    return (u & 0x80000000u) ? ~u : (u | 0x80000000u);
}
__device__ __forceinline__ float dec_f32(unsigned u) {
    return (u & 0x80000000u) ? __uint_as_float(u & 0x7fffffffu) : __uint_as_float(~u);
}
__device__ __forceinline__ float leaky(float v) { return v >= 0.f ? v : 0.2f*v; }
__device__ __forceinline__ ushort f2bf(float f) {
    unsigned u = __float_as_uint(f);
    unsigned r = (u + 0x7fffu + ((u >> 16) & 1u)) >> 16;   // RNE
    return (ushort)r;
}

// decode edge e -> (dst node, full_src value fs)
__device__ __forceinline__ void edge_decode(int e, const int* __restrict__ ei,
                                            const int* __restrict__ bi,
                                            int& dst, int& fs) {
    if (e < E_BOND)               { dst = ei[E_BOND+e];  fs = ei[e]; }
    else if (e < E_BOND+B_BRIDGE) { int i = e-E_BOND;    dst = bi[B_BRIDGE+i]; fs = bi[i]; }
    else                          { int i = e-E_BOND-B_BRIDGE; dst = bi[i]; fs = bi[B_BRIDGE+i]; }
}

// ---------------- pe + gmax init ----------------
__global__ void pe_init_kernel(float* __restrict__ pe, unsigned* __restrict__ gmax) {
    int tid = threadIdx.x;              // 1024
    int c = tid >> 8, p = tid & 255;
    float expo = (float)(p & ~1) * (1.0f/256.0f);
    float div  = powf(10000.0f, expo);
    float arg  = (float)c / div;
    pe[tid] = (p & 1) ? cosf(arg) : sinf(arg);
    if (tid == 0) *gmax = 0u;
}

// ---------------- fp32 -> bf16 converts ----------------
__global__ __launch_bounds__(256) void cvt_x_kernel(const float* __restrict__ x,
                                                    ushort* __restrict__ xb) {
    const long i = (long)blockIdx.x*256 + threadIdx.x;    // float4 index
    float4 v = ((const float4*)x)[i];
    ushort4 o; o.x = f2bf(v.x); o.y = f2bf(v.y); o.z = f2bf(v.z); o.w = f2bf(v.w);
    ((ushort4*)xb)[i] = o;
}
__global__ __launch_bounds__(256) void cvt_w_kernel(const float* __restrict__ W_in,
                                                    const float* __restrict__ W_res,
                                                    ushort* __restrict__ wc) {
    const int i = blockIdx.x*256 + threadIdx.x;           // float4 index, 40960 total
    float4 v = (i < 8192) ? ((const float4*)W_in)[i] : ((const float4*)W_res)[i - 8192];
    ushort4 o; o.x = f2bf(v.x); o.y = f2bf(v.y); o.z = f2bf(v.z); o.w = f2bf(v.w);
    ((ushort4*)wc)[i] = o;
}

// ---------------- MFMA GEMM: C[m, n] = sum_k xb[m,k] * wc[n,k] ----------------
// 128x128 tile, BK=64 two-step staging, 4 waves of 64x64.
// cols 0..255 -> xl (ld 256), cols 256..1279 -> out (ld 1024).
#define LDSK 72   // 64 + 8 pad (bf16): 2-way-only LDS aliasing on frag reads
__global__ __launch_bounds__(256) void mfma_gemm(
        const ushort* __restrict__ xb, const ushort* __restrict__ wc,
        float* __restrict__ xl, float* __restrict__ outr) {
    __shared__ ushort As[128*LDSK];
    __shared__ ushort Bs[128*LDSK];
    const int tid = threadIdx.x;
    const int m0 = blockIdx.x * 128;
    const int n0 = blockIdx.y * 128;
    const int lane = tid & 63, wv = tid >> 6;
    const int wm = wv & 1, wn = wv >> 1;
    const int quad = lane >> 4, l15 = lane & 15;
    const int mbase = wm*64, nbase = wn*64;
    f32x4 acc[4][4] = {};

    for (int kt = 0; kt < 2; ++kt) {
        if (kt) __syncthreads();   // protect LDS reuse
#pragma unroll
        for (int i = 0; i < 4; ++i) {   // A: 1024 16B chunks
            int c = tid + i*256;
            int row = c >> 3, seg = c & 7;
            *(uint4*)&As[row*LDSK + seg*8] =
                *(const uint4*)(xb + (long)(m0 + row)*F_IN + kt*64 + seg*8);
        }
#pragma unroll
        for (int i = 0; i < 4; ++i) {   // B
            int c = tid + i*256;
            int row = c >> 3, seg = c & 7;
            *(uint4*)&Bs[row*LDSK + seg*8] =
                *(const uint4*)(wc + (long)(n0 + row)*F_IN + kt*64 + seg*8);
        }
        __syncthreads();
#pragma unroll
        for (int ks = 0; ks < 2; ++ks) {
            const int ko = ks*32 + quad*8;
            bf16x8 af[4], bfr[4];
#pragma unroll
            for (int mi = 0; mi < 4; ++mi)
                af[mi] = *(const bf16x8*)&As[(mbase + mi*16 + l15)*LDSK + ko];
#pragma unroll
            for (int ni = 0; ni < 4; ++ni)
                bfr[ni] = *(const bf16x8*)&Bs[(nbase + ni*16 + l15)*LDSK + ko];
#pragma unroll
            for (int mi = 0; mi < 4; ++mi)
#pragma unroll
                for (int ni = 0; ni < 4; ++ni)
                    acc[mi][ni] = __builtin_amdgcn_mfma_f32_16x16x32_bf16(
                        af[mi], bfr[ni], acc[mi][ni], 0, 0, 0);
        }
    }

    float* dst; int ld, coloff;
    if (n0 < DM) { dst = xl;   ld = DM;   coloff = n0; }
    else         { dst = outr; ld = OUTC; coloff = n0 - DM; }
#pragma unroll
    for (int mi = 0; mi < 4; ++mi) {
        const int mrow = m0 + mbase + mi*16 + quad*4;
#pragma unroll
        for (int ni = 0; ni < 4; ++ni) {
            const int col = coloff + nbase + ni*16 + l15;
#pragma unroll
            for (int r = 0; r < 4; ++r)
                dst[(long)(mrow + r)*ld + col] = acc[mi][ni][r];
        }
    }
}

// ---------------- scores + global max ----------------
__global__ __launch_bounds__(256) void scores_kernel(
        const float* __restrict__ xl, const float* __restrict__ pe,
        const int* __restrict__ ei, const int* __restrict__ bi,
        const float* __restrict__ datt, float* __restrict__ scores,
        unsigned* __restrict__ gmax) {
    const int idx = blockIdx.x * 256 + threadIdx.x;
    const int e = idx >> 5, ch = idx & 31;
    const int c = ch >> 3, h = ch & 7;
    int nA, cA, nB, cB; bool zero = false;
    if (e < E_BOND) {
        nA = ei[e]; cA = c; nB = ei[E_BOND + e]; cB = c;
    } else if (e < E_BOND + B_BRIDGE) {
        int i = e - E_BOND;
        nA = bi[B_BRIDGE + i]; cA = c;
        nB = bi[i];            cB = (c+1 < C_CH-1) ? c+1 : C_CH-1;
        zero = (c == C_CH-1);
    } else {
        int i = e - E_BOND - B_BRIDGE;
        nA = bi[i];            cA = c;
        nB = bi[B_BRIDGE + i]; cB = (c-1 > 0) ? c-1 : 0;
        zero = (c == 0);
    }
    float score = 0.f;
    if (!zero) {
        const float4* a4 = (const float4*)(xl + (long)nA*DM + h*D_DIM);
        const float4* b4 = (const float4*)(xl + (long)nB*DM + h*D_DIM);
        const float4* pa = (const float4*)(pe + cA*DM + h*D_DIM);
        const float4* pb = (const float4*)(pe + cB*DM + h*D_DIM);
        const float4* w4 = (const float4*)(datt + ch*D_DIM);
#pragma unroll
        for (int q = 0; q < 8; ++q) {
            float4 va = a4[q], vb = b4[q], fa = pa[q], fb = pb[q], w = w4[q];
            score += w.x * leaky(va.x + fa.x + vb.x + fb.x);
            score += w.y * leaky(va.y + fa.y + vb.y + fb.y);
            score += w.z * leaky(va.z + fa.z + vb.z + fb.z);
            score += w.w * leaky(va.w + fa.w + vb.w + fb.w);
        }
    }
    scores[idx] = score;
    float m = score;
#pragma unroll
    for (int off = 32; off > 0; off >>= 1)
        m = fmaxf(m, __shfl_down(m, off, 64));
    __shared__ float sm[4];
    const int lane = threadIdx.x & 63, wv = threadIdx.x >> 6;
    if (lane == 0) sm[wv] = m;
    __syncthreads();
    if (threadIdx.x == 0) {
        float mm = fmaxf(fmaxf(sm[0], sm[1]), fmaxf(sm[2], sm[3]));
        atomicMax(gmax, enc_f32(mm));
    }
}

// ---------------- CSR-bucket build ----------------
__global__ __launch_bounds__(256) void build_kernel(
        const int* __restrict__ ei, const int* __restrict__ bi,
        int* __restrict__ counts, int* __restrict__ bucket,
        int* __restrict__ gsrc) {
    const int e = blockIdx.x * 256 + threadIdx.x;
    if (e >= ET) return;
    int dst, fs;
    edge_decode(e, ei, bi, dst, fs);
    gsrc[e] = ei[fs];   // bug-faithful: x_src[full_src] == xr[src_bond[full_src]]
    int slot = atomicAdd(&counts[dst], 1);
    if (slot < CAP) bucket[dst*CAP + slot] = e;
}

// ---------------- gather: denom + aggregation + residual + bias + PReLU ----
__global__ __launch_bounds__(256) void gather_kernel(
        const float* __restrict__ xl, const float* __restrict__ pe,
        const float* __restrict__ scores, const int* __restrict__ counts,
        const int* __restrict__ bucket, const int* __restrict__ gsrc,
        const unsigned* __restrict__ gmax, const float* __restrict__ bias,
        const float* __restrict__ pw, float* __restrict__ out) {
    const int n = blockIdx.x;
    const int t = threadIdx.x;
    const int ch = t >> 3;
    const int d0 = (t & 7) * 4;
    const int h = ch & 7, c = ch >> 3;
    const float m = dec_f32(*gmax);
    const int cnt = min(counts[n], CAP);

    float den = 0.f;
    for (int i = 0; i < cnt; ++i) {
        int e = bucket[n*CAP + i];
        den += __expf(scores[e*32 + ch] - m);
    }
    const float inv = 1.f / (den + 1e-16f);

    const int col = ch*D_DIM + d0;
    float4 acc = *(const float4*)(out + (long)n*OUTC + col);
    const float4 pv = *(const float4*)(pe + c*DM + h*D_DIM + d0);
    for (int i = 0; i < cnt; ++i) {
        int e = bucket[n*CAP + i];
        float a = __expf(scores[e*32 + ch] - m) * inv;
        int g = gsrc[e];
        float4 xv = *(const float4*)(xl + (long)g*DM + h*D_DIM + d0);
        acc.x += a*(xv.x + pv.x);
        acc.y += a*(xv.y + pv.y);
        acc.z += a*(xv.z + pv.z);
        acc.w += a*(xv.w + pv.w);
    }

    const float4 b = *(const float4*)(bias + col);
    const float w = *pw;
    float r0 = acc.x + b.x, r1 = acc.y + b.y, r2 = acc.z + b.z, r3 = acc.w + b.w;
    r0 = r0 >= 0.f ? r0 : w*r0;
    r1 = r1 >= 0.f ? r1 : w*r1;
    r2 = r2 >= 0.f ? r2 : w*r2;
    r3 = r3 >= 0.f ? r3 : w*r3;
    *(float4*)(out + (long)n*OUTC + col) = make_float4(r0, r1, r2, r3);
}

extern "C" void kernel_launch(void* const* d_in, const int* in_sizes, int n_in,
                              void* d_out, int out_size, void* d_ws, size_t ws_size,
                              hipStream_t stream) {
    const float* x     = (const float*)d_in[0];
    const int*   ei    = (const int*)d_in[1];
    const int*   bi    = (const int*)d_in[2];
    const float* W_in  = (const float*)d_in[3];
    const float* datt  = (const float*)d_in[4];
    const float* W_res = (const float*)d_in[5];
    const float* bias  = (const float*)d_in[6];
    const float* pw    = (const float*)d_in[7];
    float* out = (float*)d_out;
    char*  ws  = (char*)d_ws;

    float*    xl     = (float*)(ws + WS_XL);
    float*    pe     = (float*)(ws + WS_PE);
    float*    scores = (float*)(ws + WS_SCORES);
    int*      gsrc   = (int*)(ws + WS_GSRC);
    int*      counts = (int*)(ws + WS_CNT);
    int*      bucket = (int*)(ws + WS_BUCKET);
    unsigned* gmax   = (unsigned*)(ws + WS_GMAX);
    ushort*   xb     = (ushort*)(ws + WS_XB);
    ushort*   wc     = (ushort*)(ws + WS_WC);

    hipMemsetAsync(counts, 0, (size_t)N_NODES*4, stream);
    pe_init_kernel<<<1, 1024, 0, stream>>>(pe, gmax);
    cvt_x_kernel<<<(N_NODES*F_IN/4)/256, 256, 0, stream>>>(x, xb);
    cvt_w_kernel<<<(NCOLS*F_IN/4 + 255)/256, 256, 0, stream>>>(W_in, W_res, wc);
    {
        dim3 grid(N_NODES/128, NCOLS/128);
        mfma_gemm<<<grid, 256, 0, stream>>>(xb, wc, xl, out);
    }
    scores_kernel<<<ET*32/256, 256, 0, stream>>>(xl, pe, ei, bi, datt, scores, gmax);
    build_kernel<<<(ET+255)/256, 256, 0, stream>>>(ei, bi, counts, bucket, gsrc);
    gather_kernel<<<N_NODES, 256, 0, stream>>>(xl, pe, scores, counts, bucket,
                                               gsrc, gmax, bias, pw, out);
}

// Round 4
// 320.106 us; speedup vs baseline: 5.4524x; 1.3224x over previous
//
#include <hip/hip_runtime.h>
#include <math.h>

#define N_NODES 32768
#define F_IN    128
#define C_CH    4
#define H_HEADS 8
#define D_DIM   32
#define DM      256
#define E_BOND  65536
#define B_BRIDGE 8192
#define ET      (E_BOND + 2*B_BRIDGE)   // 81920
#define OUTC    1024                    // C*H*D
#define CAP     24                      // bucket capacity per dst node
#define NCOLS   1280                    // DM + OUTC combined GEMM width

// ---- workspace layout (bytes) ----
#define WS_XL     0u
#define WS_PE     33554432u             // + N*DM*4
#define WS_SCORES 33558528u             // + 1024*4       (ET*32*4 = 10.49 MB)
#define WS_GSRC   44044288u             // + ET*32*4
#define WS_CNT    44371968u             // + ET*4
#define WS_BUCKET 44503040u             // + N*4
#define WS_GMAX   47648768u             // + N*CAP*4
// bf16 staging overlays the scores region (scores written later in-stream):
#define WS_XB     WS_SCORES             // N*128*2 = 8,388,608
#define WS_WC     (WS_SCORES + 8388608u) // NCOLS*128*2 = 327,680  (ends < WS_GSRC)

typedef __attribute__((ext_vector_type(8))) short bf16x8;
typedef __attribute__((ext_vector_type(4))) float f32x4;

__device__ __forceinline__ unsigned enc_f32(float f) {
    unsigned u = __float_as_uint(f);
    return (u & 0x80000000u) ? ~u : (u | 0x80000000u);
}
__device__ __forceinline__ float dec_f32(unsigned u) {
    return (u & 0x80000000u) ? __uint_as_float(u & 0x7fffffffu) : __uint_as_float(~u);
}
__device__ __forceinline__ float leaky(float v) { return v >= 0.f ? v : 0.2f*v; }
__device__ __forceinline__ ushort f2bf(float f) {
    unsigned u = __float_as_uint(f);
    unsigned r = (u + 0x7fffu + ((u >> 16) & 1u)) >> 16;   // RNE
    return (ushort)r;
}

// decode edge e -> (dst node, full_src value fs)
__device__ __forceinline__ void edge_decode(int e, const int* __restrict__ ei,
                                            const int* __restrict__ bi,
                                            int& dst, int& fs) {
    if (e < E_BOND)               { dst = ei[E_BOND+e];  fs = ei[e]; }
    else if (e < E_BOND+B_BRIDGE) { int i = e-E_BOND;    dst = bi[B_BRIDGE+i]; fs = bi[i]; }
    else                          { int i = e-E_BOND-B_BRIDGE; dst = bi[i]; fs = bi[B_BRIDGE+i]; }
}

// ---------------- pe + gmax init ----------------
__global__ void pe_init_kernel(float* __restrict__ pe, unsigned* __restrict__ gmax) {
    int tid = threadIdx.x;              // 1024
    int c = tid >> 8, p = tid & 255;
    float expo = (float)(p & ~1) * (1.0f/256.0f);
    float div  = powf(10000.0f, expo);
    float arg  = (float)c / div;
    pe[tid] = (p & 1) ? cosf(arg) : sinf(arg);
    if (tid == 0) *gmax = 0u;
}

// ---------------- fp32 -> bf16 converts ----------------
__global__ __launch_bounds__(256) void cvt_x_kernel(const float* __restrict__ x,
                                                    ushort* __restrict__ xb) {
    const long i = (long)blockIdx.x*256 + threadIdx.x;    // float4 index
    float4 v = ((const float4*)x)[i];
    ushort4 o; o.x = f2bf(v.x); o.y = f2bf(v.y); o.z = f2bf(v.z); o.w = f2bf(v.w);
    ((ushort4*)xb)[i] = o;
}
__global__ __launch_bounds__(256) void cvt_w_kernel(const float* __restrict__ W_in,
                                                    const float* __restrict__ W_res,
                                                    ushort* __restrict__ wc) {
    const int i = blockIdx.x*256 + threadIdx.x;           // float4 index, 40960 total
    float4 v = (i < 8192) ? ((const float4*)W_in)[i] : ((const float4*)W_res)[i - 8192];
    ushort4 o; o.x = f2bf(v.x); o.y = f2bf(v.y); o.z = f2bf(v.z); o.w = f2bf(v.w);
    ((ushort4*)wc)[i] = o;
}

// ---------------- MFMA GEMM: C[m, n] = sum_k xb[m,k] * wc[n,k] ----------------
#define LDSK 72   // 64 + 8 pad (bf16)
__global__ __launch_bounds__(256) void mfma_gemm(
        const ushort* __restrict__ xb, const ushort* __restrict__ wc,
        float* __restrict__ xl, float* __restrict__ outr) {
    __shared__ ushort As[128*LDSK];
    __shared__ ushort Bs[128*LDSK];
    const int tid = threadIdx.x;
    const int m0 = blockIdx.x * 128;
    const int n0 = blockIdx.y * 128;
    const int lane = tid & 63, wv = tid >> 6;
    const int wm = wv & 1, wn = wv >> 1;
    const int quad = lane >> 4, l15 = lane & 15;
    const int mbase = wm*64, nbase = wn*64;
    f32x4 acc[4][4] = {};

    for (int kt = 0; kt < 2; ++kt) {
        if (kt) __syncthreads();
#pragma unroll
        for (int i = 0; i < 4; ++i) {
            int c = tid + i*256;
            int row = c >> 3, seg = c & 7;
            *(uint4*)&As[row*LDSK + seg*8] =
                *(const uint4*)(xb + (long)(m0 + row)*F_IN + kt*64 + seg*8);
        }
#pragma unroll
        for (int i = 0; i < 4; ++i) {
            int c = tid + i*256;
            int row = c >> 3, seg = c & 7;
            *(uint4*)&Bs[row*LDSK + seg*8] =
                *(const uint4*)(wc + (long)(n0 + row)*F_IN + kt*64 + seg*8);
        }
        __syncthreads();
#pragma unroll
        for (int ks = 0; ks < 2; ++ks) {
            const int ko = ks*32 + quad*8;
            bf16x8 af[4], bfr[4];
#pragma unroll
            for (int mi = 0; mi < 4; ++mi)
                af[mi] = *(const bf16x8*)&As[(mbase + mi*16 + l15)*LDSK + ko];
#pragma unroll
            for (int ni = 0; ni < 4; ++ni)
                bfr[ni] = *(const bf16x8*)&Bs[(nbase + ni*16 + l15)*LDSK + ko];
#pragma unroll
            for (int mi = 0; mi < 4; ++mi)
#pragma unroll
                for (int ni = 0; ni < 4; ++ni)
                    acc[mi][ni] = __builtin_amdgcn_mfma_f32_16x16x32_bf16(
                        af[mi], bfr[ni], acc[mi][ni], 0, 0, 0);
        }
    }

    float* dst; int ld, coloff;
    if (n0 < DM) { dst = xl;   ld = DM;   coloff = n0; }
    else         { dst = outr; ld = OUTC; coloff = n0 - DM; }
#pragma unroll
    for (int mi = 0; mi < 4; ++mi) {
        const int mrow = m0 + mbase + mi*16 + quad*4;
#pragma unroll
        for (int ni = 0; ni < 4; ++ni) {
            const int col = coloff + nbase + ni*16 + l15;
#pragma unroll
            for (int r = 0; r < 4; ++r)
                dst[(long)(mrow + r)*ld + col] = acc[mi][ni][r];
        }
    }
}

// ---------------- scores: one wave per edge, grid-strided ----------------
// lane l owns floats [4l, 4l+4) of the 256-wide row: h = l>>3, d0 = (l&7)*4
__global__ __launch_bounds__(256) void scores_kernel(
        const float* __restrict__ xl, const float* __restrict__ pe,
        const int* __restrict__ ei, const int* __restrict__ bi,
        const float* __restrict__ datt, float* __restrict__ scores,
        unsigned* __restrict__ gmax) {
    const int tid = threadIdx.x;
    const int l = tid & 63, wv = tid >> 6;
    const int pos = l * 4;
    const int h = l >> 3, dq = l & 7;

    // per-lane constants: pe[c][pos..] and datt[c*8+h][dq*4..] for c=0..3
    float4 pe4[4], w4[4];
#pragma unroll
    for (int c = 0; c < 4; ++c) {
        pe4[c] = *(const float4*)(pe + c*DM + pos);
        w4[c]  = *(const float4*)(datt + (c*H_HEADS + h)*D_DIM + dq*4);
    }

    float wmax = -1e30f;
    const int stride = gridDim.x * 4;
    for (int e = blockIdx.x*4 + wv; e < ET; e += stride) {
        int nA, nB, type;
        if (e < E_BOND) {
            nA = ei[e]; nB = ei[E_BOND + e]; type = 0;
        } else if (e < E_BOND + B_BRIDGE) {
            int i = e - E_BOND;
            nA = bi[B_BRIDGE + i]; nB = bi[i]; type = 1;   // dst_bridge + src_bridge[next]
        } else {
            int i = e - E_BOND - B_BRIDGE;
            nA = bi[i]; nB = bi[B_BRIDGE + i]; type = 2;   // src_bridge + dst_bridge[prev]
        }
        float4 a = *(const float4*)(xl + (long)nA*DM + pos);
        float4 b = *(const float4*)(xl + (long)nB*DM + pos);
        float4 s = make_float4(a.x + b.x, a.y + b.y, a.z + b.z, a.w + b.w);

        float p[4];
#pragma unroll
        for (int c = 0; c < 4; ++c) {
            int cB = (type == 0) ? c : (type == 1 ? (c+1 < 3 ? c+1 : 3)
                                                  : (c-1 > 0 ? c-1 : 0));
            bool z = (type == 1 && c == 3) || (type == 2 && c == 0);
            float4 pa = pe4[c];
            float4 pb = (cB == 0) ? pe4[0] : (cB == 1) ? pe4[1]
                       : (cB == 2) ? pe4[2] : pe4[3];
            float v0 = leaky(s.x + pa.x + pb.x);
            float v1 = leaky(s.y + pa.y + pb.y);
            float v2 = leaky(s.z + pa.z + pb.z);
            float v3 = leaky(s.w + pa.w + pb.w);
            float d = w4[c].x*v0 + w4[c].y*v1 + w4[c].z*v2 + w4[c].w*v3;
            p[c] = z ? 0.f : d;
            // reduce over the 8 lanes of this head group
            p[c] += __shfl_xor(p[c], 1);
            p[c] += __shfl_xor(p[c], 2);
            p[c] += __shfl_xor(p[c], 4);
        }
        // lanes with dq<4 write score for (c=dq, h): one 128B segment per edge
        float val = (dq == 0) ? p[0] : (dq == 1) ? p[1] : (dq == 2) ? p[2] : p[3];
        if (dq < 4) scores[(long)e*32 + dq*8 + h] = val;
        wmax = fmaxf(wmax, fmaxf(fmaxf(p[0], p[1]), fmaxf(p[2], p[3])));
    }

    // wave max (within-8 already uniform) -> block max -> global
    wmax = fmaxf(wmax, __shfl_xor(wmax, 8));
    wmax = fmaxf(wmax, __shfl_xor(wmax, 16));
    wmax = fmaxf(wmax, __shfl_xor(wmax, 32));
    __shared__ float sm[4];
    if (l == 0) sm[wv] = wmax;
    __syncthreads();
    if (tid == 0) {
        float mm = fmaxf(fmaxf(sm[0], sm[1]), fmaxf(sm[2], sm[3]));
        atomicMax(gmax, enc_f32(mm));
    }
}

// ---------------- CSR-bucket build ----------------
__global__ __launch_bounds__(256) void build_kernel(
        const int* __restrict__ ei, const int* __restrict__ bi,
        int* __restrict__ counts, int* __restrict__ bucket,
        int* __restrict__ gsrc) {
    const int e = blockIdx.x * 256 + threadIdx.x;
    if (e >= ET) return;
    int dst, fs;
    edge_decode(e, ei, bi, dst, fs);
    gsrc[e] = ei[fs];   // bug-faithful: x_src[full_src] == xr[src_bond[full_src]]
    int slot = atomicAdd(&counts[dst], 1);
    if (slot < CAP) bucket[dst*CAP + slot] = e;
}

// ---------------- gather: denom + aggregation + residual + bias + PReLU ----
__global__ __launch_bounds__(256) void gather_kernel(
        const float* __restrict__ xl, const float* __restrict__ pe,
        const float* __restrict__ scores, const int* __restrict__ counts,
        const int* __restrict__ bucket, const int* __restrict__ gsrc,
        const unsigned* __restrict__ gmax, const float* __restrict__ bias,
        const float* __restrict__ pw, float* __restrict__ out) {
    const int n = blockIdx.x;
    const int t = threadIdx.x;
    const int ch = t >> 3;
    const int d0 = (t & 7) * 4;
    const int h = ch & 7, c = ch >> 3;
    const float m = dec_f32(*gmax);
    const int cnt = min(counts[n], CAP);

    float den = 0.f;
    for (int i = 0; i < cnt; ++i) {
        int e = bucket[n*CAP + i];
        den += __expf(scores[e*32 + ch] - m);
    }
    const float inv = 1.f / (den + 1e-16f);

    const int col = ch*D_DIM + d0;
    float4 acc = *(const float4*)(out + (long)n*OUTC + col);
    const float4 pv = *(const float4*)(pe + c*DM + h*D_DIM + d0);
    for (int i = 0; i < cnt; ++i) {
        int e = bucket[n*CAP + i];
        float a = __expf(scores[e*32 + ch] - m) * inv;
        int g = gsrc[e];
        float4 xv = *(const float4*)(xl + (long)g*DM + h*D_DIM + d0);
        acc.x += a*(xv.x + pv.x);
        acc.y += a*(xv.y + pv.y);
        acc.z += a*(xv.z + pv.z);
        acc.w += a*(xv.w + pv.w);
    }

    const float4 b = *(const float4*)(bias + col);
    const float w = *pw;
    float r0 = acc.x + b.x, r1 = acc.y + b.y, r2 = acc.z + b.z, r3 = acc.w + b.w;
    r0 = r0 >= 0.f ? r0 : w*r0;
    r1 = r1 >= 0.f ? r1 : w*r1;
    r2 = r2 >= 0.f ? r2 : w*r2;
    r3 = r3 >= 0.f ? r3 : w*r3;
    *(float4*)(out + (long)n*OUTC + col) = make_float4(r0, r1, r2, r3);
}

extern "C" void kernel_launch(void* const* d_in, const int* in_sizes, int n_in,
                              void* d_out, int out_size, void* d_ws, size_t ws_size,
                              hipStream_t stream) {
    const float* x     = (const float*)d_in[0];
    const int*   ei    = (const int*)d_in[1];
    const int*   bi    = (const int*)d_in[2];
    const float* W_in  = (const float*)d_in[3];
    const float* datt  = (const float*)d_in[4];
    const float* W_res = (const float*)d_in[5];
    const float* bias  = (const float*)d_in[6];
    const float* pw    = (const float*)d_in[7];
    float* out = (float*)d_out;
    char*  ws  = (char*)d_ws;

    float*    xl     = (float*)(ws + WS_XL);
    float*    pe     = (float*)(ws + WS_PE);
    float*    scores = (float*)(ws + WS_SCORES);
    int*      gsrc   = (int*)(ws + WS_GSRC);
    int*      counts = (int*)(ws + WS_CNT);
    int*      bucket = (int*)(ws + WS_BUCKET);
    unsigned* gmax   = (unsigned*)(ws + WS_GMAX);
    ushort*   xb     = (ushort*)(ws + WS_XB);
    ushort*   wc     = (ushort*)(ws + WS_WC);

    hipMemsetAsync(counts, 0, (size_t)N_NODES*4, stream);
    pe_init_kernel<<<1, 1024, 0, stream>>>(pe, gmax);
    cvt_x_kernel<<<(N_NODES*F_IN/4)/256, 256, 0, stream>>>(x, xb);
    cvt_w_kernel<<<(NCOLS*F_IN/4 + 255)/256, 256, 0, stream>>>(W_in, W_res, wc);
    {
        dim3 grid(N_NODES/128, NCOLS/128);
        mfma_gemm<<<grid, 256, 0, stream>>>(xb, wc, xl, out);
    }
    scores_kernel<<<2048, 256, 0, stream>>>(xl, pe, ei, bi, datt, scores, gmax);
    build_kernel<<<(ET+255)/256, 256, 0, stream>>>(ei, bi, counts, bucket, gsrc);
    gather_kernel<<<N_NODES, 256, 0, stream>>>(xl, pe, scores, counts, bucket,
                                               gsrc, gmax, bias, pw, out);
}